// Round 6
// baseline (32.173 us; speedup 1.0000x reference)
//
#include <hip/hip_runtime.h>
#include <math.h>

#define DIM_   128
#define NAT_   16
#define NTOT_  1024
#define BMOL_  64
#define NBLK_  256     // 4 sub-blocks per molecule
#define OFFB_  1008.0f
#define EPSF_  1e-12f

// Single fused kernel: 256 blocks x 512 threads. Block bid: molecule m=bid>>2,
// sub-block sub=bid&3 (owns atoms 4*sub..4*sub+3 for gather/publish).
// Phase 1 (all blocks): embed -> contri (k-split over 4 slots, W_fp read once)
//   -> message+L2norm (all 16 atoms, duplicated x4) -> bond gather for own 4
//   atoms (16 batched loads/thread) -> publish per-block Sb/TnIn partials.
// Grid barrier. Phase 2 (sub==0 blocks only): S -> tn -> MLP -> out.
__global__ __launch_bounds__(512) void fused(
    const int* __restrict__ fp, const float* __restrict__ Efp,
    const float* __restrict__ Wfp, const float* __restrict__ bfp,
    const float* __restrict__ adj, const int* __restrict__ bidx,
    const float* __restrict__ Ebond,
    const float* __restrict__ W0, const float* __restrict__ b0,
    const float* __restrict__ W1, const float* __restrict__ b1,
    const float* __restrict__ Wp, const float* __restrict__ bp,
    float* __restrict__ SbP_g, float* __restrict__ TnP_g,
    unsigned* __restrict__ bar, float* __restrict__ out)
{
    const int bid = blockIdx.x;
    const int m = bid >> 2, sub = bid & 3, base = m * NAT_;
    const int t = threadIdx.x;
    const int c = t & 127;      // dim
    const int s = t >> 7;       // slot 0..3

    __shared__ float mpsS[NAT_][DIM_];      // embeddings -> mpsn
    __shared__ float conP[4][NAT_][DIM_];   // k-split contri partials (32 KB)
    __shared__ float conS[NAT_][DIM_];
    __shared__ float adjS[NAT_][NAT_];
    __shared__ int   bSh[4][NAT_];          // bond rows of our 4 atoms
    __shared__ float nrmRed[NAT_][2];
    __shared__ float nrmS[NAT_];
    __shared__ float w4[4][DIM_];
    __shared__ float sb4[4][DIM_];
    __shared__ float mbS[DIM_];
    __shared__ float vS[DIM_];
    __shared__ float tnS[DIM_];
    __shared__ float r2[2];

    // ---- loads ----
    #pragma unroll
    for (int r = 0; r < 4; ++r) {
        const int idx = t + r * 512;
        const int j = idx >> 7, cc = idx & 127;
        mpsS[j][cc] = Efp[(size_t)fp[base + j] * DIM_ + cc];
    }
    if (t < 256) {
        const int j = t >> 4, i = t & 15;
        adjS[j][i] = adj[(size_t)(base + j) * NTOT_ + base + i];
    } else if (t < 320) {
        const int tt = t - 256, j = tt >> 4, i = tt & 15;
        bSh[j][i] = bidx[(size_t)(base + 4 * sub + j) * NTOT_ + base + i];
    }
    __syncthreads();

    // ---- contri, k-split: slot s covers k in [32s, 32s+32), all 16 atoms ----
    {
        float a[NAT_];
        #pragma unroll
        for (int j = 0; j < NAT_; ++j) a[j] = 0.0f;
        #pragma unroll 4
        for (int kk = 0; kk < 32; ++kk) {
            const int k = (s << 5) + kk;
            const float w = Wfp[(size_t)k * DIM_ + c];
            #pragma unroll
            for (int j = 0; j < NAT_; ++j) a[j] += mpsS[j][k] * w;
        }
        #pragma unroll
        for (int j = 0; j < NAT_; ++j) conP[s][j][c] = a[j];
    }
    __syncthreads();
    #pragma unroll
    for (int r = 0; r < 4; ++r) {
        const int idx = t + r * 512;
        const int j = idx >> 7, cc = idx & 127;
        conS[j][cc] = fmaxf(conP[0][j][cc] + conP[1][j][cc] + conP[2][j][cc]
                          + conP[3][j][cc] + bfp[cc], 0.0f);
    }
    __syncthreads();

    // ---- messages + norms for ALL 16 atoms: slot s does atoms s, s+4, s+8, s+12
    float msv[4];
    #pragma unroll
    for (int u = 0; u < 4; ++u) {
        const int i = s + 4 * u;
        float x = mpsS[i][c];
        #pragma unroll
        for (int q = 0; q < NAT_; ++q) x += adjS[i][q] * conS[q][c];
        msv[u] = x;
        float v = x * x;
        #pragma unroll
        for (int o = 32; o > 0; o >>= 1) v += __shfl_xor(v, o, 64);
        if ((t & 63) == 0) nrmRed[i][(t >> 6) & 1] = v;
    }
    __syncthreads();
    if (t < NAT_) nrmS[t] = fmaxf(sqrtf(nrmRed[t][0] + nrmRed[t][1]), EPSF_);
    __syncthreads();
    #pragma unroll
    for (int u = 0; u < 4; ++u) {
        const int i = s + 4 * u;
        mpsS[i][c] = msv[u] / nrmS[i];      // mpsn
    }
    __syncthreads();

    // ---- bond gather for own atom j = 4*sub + s (16 batched loads) ----
    {
        const float e0 = Ebond[c];
        float nsq = OFFB_ * e0 * e0;
        float ev[NAT_];
        int bb[NAT_];
        #pragma unroll
        for (int i = 0; i < NAT_; ++i) bb[i] = bSh[s][i];
        #pragma unroll
        for (int i = 0; i < NAT_; ++i) ev[i] = Ebond[(size_t)bb[i] * DIM_ + c];
        #pragma unroll
        for (int i = 0; i < NAT_; ++i) nsq += ev[i] * ev[i];
        const float msc = mpsS[4 * sub + s][c] / fmaxf(sqrtf(nsq), EPSF_);
        float tj = 0.0f;
        #pragma unroll
        for (int i = 0; i < NAT_; ++i) tj += ev[i] * mpsS[i][c];
        w4[s][c]  = msc * tj;
        sb4[s][c] = msc;
    }
    __syncthreads();

    // ---- publish per-block partials (agent scope) ----
    if (s == 0) {
        const float TnP = w4[0][c] + w4[1][c] + w4[2][c] + w4[3][c];
        const float SbP = sb4[0][c] + sb4[1][c] + sb4[2][c] + sb4[3][c];
        __hip_atomic_store(&TnP_g[(size_t)bid * DIM_ + c], TnP, __ATOMIC_RELAXED, __HIP_MEMORY_SCOPE_AGENT);
        __hip_atomic_store(&SbP_g[(size_t)bid * DIM_ + c], SbP, __ATOMIC_RELAXED, __HIP_MEMORY_SCOPE_AGENT);
    }
    if (sub == 0 && s == 1) {
        float mb = 0.0f;
        #pragma unroll
        for (int i = 0; i < NAT_; ++i) mb += mpsS[i][c];
        mbS[c] = mb;                        // LDS only; consumed after barrier
    }
    __syncthreads();

    // ---- grid barrier ----
    if (t == 0) {
        __threadfence();
        __hip_atomic_fetch_add(bar, 1u, __ATOMIC_ACQ_REL, __HIP_MEMORY_SCOPE_AGENT);
    }
    if (sub != 0) return;                   // arrival done; 192 blocks exit
    if (t == 0) {
        unsigned cur;
        do {
            __builtin_amdgcn_s_sleep(2);
            cur = __hip_atomic_load(bar, __ATOMIC_ACQUIRE, __HIP_MEMORY_SCOPE_AGENT);
        } while (cur < (unsigned)NBLK_);
    }
    __syncthreads();

    // ---- phase 2 (sub==0 blocks): S over 256 partials, slot-split ----
    {
        float S = 0.0f;
        for (int rb = 0; rb < 4; ++rb) {
            float tv[16];
            #pragma unroll
            for (int r = 0; r < 16; ++r)
                tv[r] = __hip_atomic_load(&SbP_g[(size_t)(s * 64 + rb * 16 + r) * DIM_ + c],
                                          __ATOMIC_RELAXED, __HIP_MEMORY_SCOPE_AGENT);
            #pragma unroll
            for (int r = 0; r < 16; ++r) S += tv[r];
        }
        w4[s][c] = S;
    }
    __syncthreads();
    if (s == 0) {
        const float Sall = w4[0][c] + w4[1][c] + w4[2][c] + w4[3][c];
        float Sb_m = 0.0f, Tn_m = 0.0f;
        #pragma unroll
        for (int u = 0; u < 4; ++u) {
            Sb_m += __hip_atomic_load(&SbP_g[(size_t)(4 * m + u) * DIM_ + c],
                                      __ATOMIC_RELAXED, __HIP_MEMORY_SCOPE_AGENT);
            Tn_m += __hip_atomic_load(&TnP_g[(size_t)(4 * m + u) * DIM_ + c],
                                      __ATOMIC_RELAXED, __HIP_MEMORY_SCOPE_AGENT);
        }
        vS[c] = Tn_m + Ebond[c] * (Sall - Sb_m) * mbS[c];   // tn
    }
    __syncthreads();

    // ---- MLP: layer 1 (d-loop split over slots) ----
    {
        float a1 = 0.0f;
        #pragma unroll 8
        for (int r = 0; r < 32; ++r) {
            const int d = s * 32 + r;
            a1 += vS[d] * W0[(size_t)d * DIM_ + c];
        }
        w4[s][c] = a1;
    }
    __syncthreads();
    if (s == 0) tnS[c] = fmaxf(w4[0][c] + w4[1][c] + w4[2][c] + w4[3][c] + b0[c], 0.0f);
    __syncthreads();
    {
        float a2 = 0.0f;
        #pragma unroll 8
        for (int r = 0; r < 32; ++r) {
            const int d = s * 32 + r;
            a2 += tnS[d] * W1[(size_t)d * DIM_ + c];
        }
        w4[s][c] = a2;
    }
    __syncthreads();
    if (s == 0) {
        const float x1 = fmaxf(w4[0][c] + w4[1][c] + w4[2][c] + w4[3][c] + b1[c], 0.0f);
        float vv = x1 * Wp[c];
        #pragma unroll
        for (int o = 32; o > 0; o >>= 1) vv += __shfl_xor(vv, o, 64);
        if ((c & 63) == 0) r2[c >> 6] = vv;
    }
    __syncthreads();
    if (t == 0) out[m] = r2[0] + r2[1] + bp[0];
}

extern "C" void kernel_launch(void* const* d_in, const int* in_sizes, int n_in,
                              void* d_out, int out_size, void* d_ws, size_t ws_size,
                              hipStream_t stream) {
    const int*   fingerprints = (const int*)  d_in[0];
    const float* adjacency    = (const float*)d_in[1];
    const int*   bond_index   = (const int*)  d_in[2];
    const float* E_fp         = (const float*)d_in[3];
    const float* E_bond       = (const float*)d_in[4];
    const float* W_fp         = (const float*)d_in[5];
    const float* b_fp         = (const float*)d_in[6];
    const float* W_out0       = (const float*)d_in[7];
    const float* b_out0       = (const float*)d_in[8];
    const float* W_out1       = (const float*)d_in[9];
    const float* b_out1       = (const float*)d_in[10];
    const float* W_prop       = (const float*)d_in[11];
    const float* b_prop       = (const float*)d_in[12];
    float* out = (float*)d_out;

    float* ws = (float*)d_ws;
    const size_t PD = (size_t)NBLK_ * DIM_;
    float* SbP = ws;                 // [256,128]
    float* TnP = ws + PD;            // [256,128]
    unsigned* bar = (unsigned*)(ws + 2 * PD);

    hipMemsetAsync(bar, 0, sizeof(unsigned), stream);
    fused<<<NBLK_, 512, 0, stream>>>(fingerprints, E_fp, W_fp, b_fp,
                                     adjacency, bond_index, E_bond,
                                     W_out0, b_out0, W_out1, b_out1, W_prop, b_prop,
                                     SbP, TnP, bar, out);
}

// Round 7
// 18.608 us; speedup vs baseline: 1.7290x; 1.7290x over previous
//
#include <hip/hip_runtime.h>
#include <math.h>

#define DIM_   128
#define NAT_   16
#define NTOT_  1024
#define BMOL_  64
#define OFFB_  1008.0f
#define EPSF_  1e-12f

// Kernel A: 128 blocks (2 per molecule) x 1024 threads (16 waves).
// Block b: m = b>>1, half h = b&1 (owns atoms 8h..8h+7 for the bond gather).
// Thread t: c = t&127 (dim), s = t>>7 (slot 0..7).
// Full contri/message/L2norm computed in every block (cheap, duplicated x2);
// bond gather + Sb/TnIn partials only for the 8 owned atoms (16 loads/thread).
__global__ __launch_bounds__(1024) void kA(const int* __restrict__ fp,
                                           const float* __restrict__ Efp,
                                           const float* __restrict__ Wfp,
                                           const float* __restrict__ bfp,
                                           const float* __restrict__ adj,
                                           const int* __restrict__ bidx,
                                           const float* __restrict__ Ebond,
                                           float* __restrict__ TnP_g,   // [128,128]
                                           float* __restrict__ SbP_g,   // [128,128]
                                           float* __restrict__ Mb_g) {  // [64,128]
    const int b = blockIdx.x;
    const int m = b >> 1, h = b & 1, base = m * NAT_;
    const int t = threadIdx.x;
    const int c = t & 127;
    const int s = t >> 7;
    const int j0 = 2 * s, j1 = 2 * s + 1;   // contri/message atoms
    const int jg = 8 * h + s;               // gather-owned atom

    __shared__ float mpsS[NAT_][DIM_];      // embeddings -> mpsn
    __shared__ float conS[NAT_][DIM_];
    __shared__ float adjS[NAT_][NAT_];
    __shared__ int   bSh[8][NAT_];
    __shared__ float redS[NAT_][2];
    __shared__ float nrmS[NAT_];
    __shared__ float sb8[8][DIM_];
    __shared__ float tnp8[8][DIM_];

    // embeddings: 2048 elems / 1024 threads = 2 each
    {
        int j = t >> 7, cc = t & 127;
        mpsS[j][cc] = Efp[(size_t)fp[base + j] * DIM_ + cc];
        j += 8;
        mpsS[j][cc] = Efp[(size_t)fp[base + j] * DIM_ + cc];
    }
    if (t < 256) {
        const int j = t >> 4, i = t & 15;
        adjS[j][i] = adj[(size_t)(base + j) * NTOT_ + base + i];
    } else if (t < 384) {
        const int tt = t - 256, j = tt >> 4, i = tt & 15;
        bSh[j][i] = bidx[(size_t)(base + 8 * h + j) * NTOT_ + base + i];
    }
    __syncthreads();

    // contri for atoms j0, j1
    float a0 = bfp[c];
    float a1 = a0;
    #pragma unroll 8
    for (int k = 0; k < DIM_; ++k) {
        const float w = Wfp[(size_t)k * DIM_ + c];
        a0 += mpsS[j0][k] * w;
        a1 += mpsS[j1][k] * w;
    }
    conS[j0][c] = fmaxf(a0, 0.0f);
    conS[j1][c] = fmaxf(a1, 0.0f);
    __syncthreads();

    // message + row L2 norm for atoms j0, j1
    float ms0 = mpsS[j0][c], ms1 = mpsS[j1][c];
    #pragma unroll
    for (int i = 0; i < NAT_; ++i) {
        const float cv = conS[i][c];
        ms0 += adjS[j0][i] * cv;
        ms1 += adjS[j1][i] * cv;
    }
    float v0 = ms0 * ms0, v1 = ms1 * ms1;
    #pragma unroll
    for (int o = 32; o > 0; o >>= 1) {
        v0 += __shfl_xor(v0, o, 64);
        v1 += __shfl_xor(v1, o, 64);
    }
    const int half = (t >> 6) & 1;
    if ((t & 63) == 0) { redS[j0][half] = v0; redS[j1][half] = v1; }
    __syncthreads();
    if (t < NAT_) nrmS[t] = fmaxf(sqrtf(redS[t][0] + redS[t][1]), EPSF_);
    __syncthreads();
    mpsS[j0][c] = ms0 / nrmS[j0];
    mpsS[j1][c] = ms1 / nrmS[j1];
    __syncthreads();

    // bond gather for owned atom jg: 16 batched loads in flight
    {
        const float e0 = Ebond[c];
        float nsq = OFFB_ * e0 * e0;
        int bb[NAT_];
        #pragma unroll
        for (int i = 0; i < NAT_; ++i) bb[i] = bSh[s][i];
        float ev[NAT_];
        #pragma unroll
        for (int i = 0; i < NAT_; ++i) ev[i] = Ebond[(size_t)bb[i] * DIM_ + c];
        #pragma unroll
        for (int i = 0; i < NAT_; ++i) nsq += ev[i] * ev[i];
        const float msc = mpsS[jg][c] / fmaxf(sqrtf(nsq), EPSF_);
        float tj = 0.0f;
        #pragma unroll
        for (int i = 0; i < NAT_; ++i) tj += ev[i] * mpsS[i][c];
        sb8[s][c]  = msc;
        tnp8[s][c] = msc * tj;
    }
    __syncthreads();

    if (s == 0) {
        float Tn = 0.0f, Sb = 0.0f;
        #pragma unroll
        for (int q = 0; q < 8; ++q) { Tn += tnp8[q][c]; Sb += sb8[q][c]; }
        TnP_g[(size_t)b * DIM_ + c] = Tn;
        SbP_g[(size_t)b * DIM_ + c] = Sb;
    } else if (s == 1 && h == 0) {
        float mb = 0.0f;
        #pragma unroll
        for (int i = 0; i < NAT_; ++i) mb += mpsS[i][c];
        Mb_g[(size_t)m * DIM_ + c] = mb;
    }
}

// Kernel B: 64 blocks x 512 threads. S -> tn -> MLP -> out, slot-split d-loops.
__global__ __launch_bounds__(512) void kB(const float* __restrict__ Ebond,
                                          const float* __restrict__ TnP_g,
                                          const float* __restrict__ SbP_g,
                                          const float* __restrict__ Mb_g,
                                          const float* __restrict__ W0, const float* __restrict__ b0,
                                          const float* __restrict__ W1, const float* __restrict__ b1,
                                          const float* __restrict__ Wp, const float* __restrict__ bp,
                                          float* __restrict__ out) {
    const int m = blockIdx.x;
    const int t = threadIdx.x;
    const int c = t & 127;
    const int s = t >> 7;
    __shared__ float w4[4][DIM_];
    __shared__ float vS[DIM_];
    __shared__ float tnS[DIM_];
    __shared__ float r2[2];

    // S: sum of 128 partials, slot s covers 32
    {
        float S = 0.0f;
        float tv[32];
        #pragma unroll
        for (int r = 0; r < 32; ++r)
            tv[r] = SbP_g[(size_t)(s * 32 + r) * DIM_ + c];
        #pragma unroll
        for (int r = 0; r < 32; ++r) S += tv[r];
        w4[s][c] = S;
    }
    __syncthreads();
    if (s == 0) {
        const float Sall = w4[0][c] + w4[1][c] + w4[2][c] + w4[3][c];
        const float Sb_m = SbP_g[(size_t)(2 * m) * DIM_ + c] + SbP_g[(size_t)(2 * m + 1) * DIM_ + c];
        const float Tn_m = TnP_g[(size_t)(2 * m) * DIM_ + c] + TnP_g[(size_t)(2 * m + 1) * DIM_ + c];
        vS[c] = Tn_m + Ebond[c] * (Sall - Sb_m) * Mb_g[(size_t)m * DIM_ + c];
    }
    __syncthreads();

    // layer 1, d-loop split over slots
    {
        float a1 = 0.0f;
        #pragma unroll 8
        for (int r = 0; r < 32; ++r) {
            const int d = s * 32 + r;
            a1 += vS[d] * W0[(size_t)d * DIM_ + c];
        }
        w4[s][c] = a1;
    }
    __syncthreads();
    if (s == 0) tnS[c] = fmaxf(w4[0][c] + w4[1][c] + w4[2][c] + w4[3][c] + b0[c], 0.0f);
    __syncthreads();
    {
        float a2 = 0.0f;
        #pragma unroll 8
        for (int r = 0; r < 32; ++r) {
            const int d = s * 32 + r;
            a2 += tnS[d] * W1[(size_t)d * DIM_ + c];
        }
        w4[s][c] = a2;
    }
    __syncthreads();
    if (s == 0) {
        const float x1 = fmaxf(w4[0][c] + w4[1][c] + w4[2][c] + w4[3][c] + b1[c], 0.0f);
        float vv = x1 * Wp[c];
        #pragma unroll
        for (int o = 32; o > 0; o >>= 1) vv += __shfl_xor(vv, o, 64);
        if ((c & 63) == 0) r2[c >> 6] = vv;
    }
    __syncthreads();
    if (t == 0) out[m] = r2[0] + r2[1] + bp[0];
}

extern "C" void kernel_launch(void* const* d_in, const int* in_sizes, int n_in,
                              void* d_out, int out_size, void* d_ws, size_t ws_size,
                              hipStream_t stream) {
    const int*   fingerprints = (const int*)  d_in[0];
    const float* adjacency    = (const float*)d_in[1];
    const int*   bond_index   = (const int*)  d_in[2];
    const float* E_fp         = (const float*)d_in[3];
    const float* E_bond       = (const float*)d_in[4];
    const float* W_fp         = (const float*)d_in[5];
    const float* b_fp         = (const float*)d_in[6];
    const float* W_out0       = (const float*)d_in[7];
    const float* b_out0       = (const float*)d_in[8];
    const float* W_out1       = (const float*)d_in[9];
    const float* b_out1       = (const float*)d_in[10];
    const float* W_prop       = (const float*)d_in[11];
    const float* b_prop       = (const float*)d_in[12];
    float* out = (float*)d_out;

    float* ws = (float*)d_ws;
    const size_t PD = (size_t)128 * DIM_;
    float* TnP = ws;                 // [128,128]
    float* SbP = ws + PD;            // [128,128]
    float* Mb  = ws + 2 * PD;        // [64,128]

    kA<<<128, 1024, 0, stream>>>(fingerprints, E_fp, W_fp, b_fp, adjacency, bond_index,
                                 E_bond, TnP, SbP, Mb);
    kB<<<BMOL_, 512, 0, stream>>>(E_bond, TnP, SbP, Mb,
                                  W_out0, b_out0, W_out1, b_out1, W_prop, b_prop, out);
}